// Round 13
// baseline (104.622 us; speedup 1.0000x reference)
//
#include <hip/hip_runtime.h>

// ---------------------------------------------------------------------------
// Clique2NodeConv: out[n] = (mean_{e: node[e]==n} x_clique[clique[e]]) @ W^T + b
// y = bf16(x_clique @ W^T) [MFMA], then bucket-sorted CSR gather-reduce.
// Pipeline (3 kernels + 32KB memset):
//   k_front : fused {MFMA transform, 256 rows/block} + {bucket partition}
//   k_build : per-bucket LDS counting sort (512 thr) -> offsets/ncnt + u16
//             edge_dst, node runs padded to multiple of 8 (zero-row sentinel)
//   k_reduce: channel-split gather — ONE uint4 instruction covers 4 y-rows
//             (lane = 4 edge-slots x 16 channel-groups); shfl_xor(16,32) epilogue
// ---------------------------------------------------------------------------

typedef short bf16x8 __attribute__((ext_vector_type(8)));
typedef float f32x4  __attribute__((ext_vector_type(4)));
typedef float f32x2  __attribute__((ext_vector_type(2)));

#define BK_SHIFT 8
#define NB_MAX 512        // max buckets (n_nodes <= 131072)
#define BCUR_STRIDE 16    // one counter per 64B line
#define RAWCAP 4608       // raw bucket capacity: mean 4096 + 8 sigma
#define PADCAP 6400       // padded capacity (ushort units): RAWCAP + 256*7
#define FCHUNK 4096       // edges per fill block

__device__ inline ushort f2b(float f) {   // f32 -> bf16 RNE
    union { float f; uint u; } v; v.f = f;
    uint r = v.u + 0x7FFFu + ((v.u >> 16) & 1u);
    return (ushort)(r >> 16);
}
__device__ inline float blo(uint v) { union { uint u; float f; } x; x.u = v << 16;        return x.f; }
__device__ inline float bhi(uint v) { union { uint u; float f; } x; x.u = v & 0xFFFF0000u; return x.f; }

struct FillSM {
    int cnt[NB_MAX];
    int sloc[NB_MAX];
    int gbase[NB_MAX];
    int cur[NB_MAX];
    int wtot[8];
    uint   stage[FCHUNK];    // packed (local8<<16)|clique16
    ushort sbkt[FCHUNK];     // bucket id of staged pair
};
struct TransSM { ushort wl[128 * 128]; };   // swizzled bf16 W

// K1 fused: blocks [0,gf) partition edges into bucket regions (bump alloc);
//           blocks [gf,gf+gt) compute y = bf16(xc @ W^T), 256 rows per block.
__global__ __launch_bounds__(512) void k_front(const float* __restrict__ xc,
                                               const float* __restrict__ W,
                                               ushort* __restrict__ yb, int nc,
                                               const int* __restrict__ nidx,
                                               const int* __restrict__ cidx,
                                               int* __restrict__ bcur,
                                               uint* __restrict__ pairs,
                                               int ne, int gf) {
    __shared__ union USM { FillSM f; TransSM tr; } sm;
    const int t = threadIdx.x;
    const int lane = t & 63, wid = t >> 6;

    if ((int)blockIdx.x < gf) {
        // ----- bucket partition -----
        const int e0 = blockIdx.x * FCHUNK;
        const int e1 = min(e0 + FCHUNK, ne);
        sm.f.cnt[t] = 0;
        sm.f.cur[t] = 0;
        __syncthreads();

        int nn[8], cc[8];
        #pragma unroll
        for (int k = 0; k < 8; ++k) {
            int i = e0 + k * 512 + t;
            if (i < e1) {
                nn[k] = nidx[i];
                cc[k] = cidx[i];
                atomicAdd(&sm.f.cnt[nn[k] >> BK_SHIFT], 1);
            } else nn[k] = -1;
        }
        __syncthreads();

        // exclusive scan of 512 bucket counts
        int v = sm.f.cnt[t];
        int inc = v;
        #pragma unroll
        for (int d = 1; d < 64; d <<= 1) { int x = __shfl_up(inc, d); if (lane >= d) inc += x; }
        if (lane == 63) sm.f.wtot[wid] = inc;
        __syncthreads();
        int wpre = 0;
        for (int i = 0; i < wid; ++i) wpre += sm.f.wtot[i];
        int excl = wpre + inc - v;
        sm.f.sloc[t] = excl;
        if (v > 0) sm.f.gbase[t] = t * RAWCAP + atomicAdd(&bcur[t * BCUR_STRIDE], v);
        __syncthreads();

        // group pairs by bucket in LDS
        #pragma unroll
        for (int k = 0; k < 8; ++k) {
            if (nn[k] >= 0) {
                int b = nn[k] >> BK_SHIFT;
                int slot = sm.f.sloc[b] + atomicAdd(&sm.f.cur[b], 1);
                sm.f.stage[slot] = ((uint)(nn[k] & 255) << 16) | (uint)cc[k];
                sm.f.sbkt[slot] = (ushort)b;
            }
        }
        __syncthreads();

        // flush coalesced runs to bucket regions
        const int m = e1 - e0;
        for (int i = t; i < m; i += 512) {
            int b = sm.f.sbkt[i];
            pairs[(size_t)sm.f.gbase[b] + (i - sm.f.sloc[b])] = sm.f.stage[i];
        }
    } else {
        // ----- transform: y = bf16(xc @ W^T), 256 rows per block -----
        const int bid = blockIdx.x - gf;
        if (bid == 0 && t < 64)     // zero the pad row y[nc]
            reinterpret_cast<uint*>(&yb[(size_t)nc * 128])[t] = 0u;
        for (int i = 0; i < 8; ++i) {
            int idx = (i * 512 + t) * 4;
            float4 w4 = *reinterpret_cast<const float4*>(&W[idx]);
            int o = idx >> 7, k = idx & 127;
            ushort4 h;
            h.x = f2b(w4.x); h.y = f2b(w4.y); h.z = f2b(w4.z); h.w = f2b(w4.w);
            int byte = o * 256 + k * 2;
            byte ^= (o & 7) << 4;
            *reinterpret_cast<ushort4*>(reinterpret_cast<char*>(sm.tr.wl) + byte) = h;
        }
        __syncthreads();

        const int lrow = lane & 15;
        const int lk = lane >> 4;
        for (int g = 0; g < 2; ++g) {
            const int r0 = bid * 256 + g * 128 + wid * 16;
            const bool rowok = (r0 + lrow) < nc;
            const float* arow = &xc[(size_t)(r0 + lrow) * 128];

            bf16x8 afrag[4];
            for (int kb = 0; kb < 4; ++kb) {
                float4 a0 = make_float4(0.f, 0.f, 0.f, 0.f), a1 = a0;
                if (rowok) {
                    int k0 = kb * 32 + lk * 8;
                    a0 = *reinterpret_cast<const float4*>(&arow[k0]);
                    a1 = *reinterpret_cast<const float4*>(&arow[k0 + 4]);
                }
                bf16x8 a;
                a[0] = (short)f2b(a0.x); a[1] = (short)f2b(a0.y);
                a[2] = (short)f2b(a0.z); a[3] = (short)f2b(a0.w);
                a[4] = (short)f2b(a1.x); a[5] = (short)f2b(a1.y);
                a[6] = (short)f2b(a1.z); a[7] = (short)f2b(a1.w);
                afrag[kb] = a;
            }

            for (int ct = 0; ct < 8; ++ct) {
                f32x4 c = {0.f, 0.f, 0.f, 0.f};
                const int o = ct * 16 + lrow;
                #pragma unroll
                for (int kb = 0; kb < 4; ++kb) {
                    int byte = o * 256 + (kb * 32 + lk * 8) * 2;
                    byte ^= (o & 7) << 4;
                    bf16x8 bb = *reinterpret_cast<const bf16x8*>(reinterpret_cast<const char*>(sm.tr.wl) + byte);
                    c = __builtin_amdgcn_mfma_f32_16x16x32_bf16(afrag[kb], bb, c, 0, 0, 0);
                }
                const int orow = r0 + lk * 4;
                #pragma unroll
                for (int j = 0; j < 4; ++j)
                    if (orow + j < nc)
                        yb[(size_t)(orow + j) * 128 + ct * 16 + lrow] = f2b(c[j]);
            }
        }
    }
}

// K2: one block (512 thr) per bucket: LDS hist, PADDED scan (runs rounded to 8),
// counting sort into u16 scidx with zero-row pad entries, stream edge_dst(u16).
__global__ __launch_bounds__(512) void k_build(const uint* __restrict__ pairs,
                                               const int* __restrict__ bcur,
                                               int* __restrict__ offsets,
                                               int* __restrict__ ncnt,
                                               ushort* __restrict__ edge_dst,
                                               int n_nodes, int nc) {
    __shared__ int arr[256], nexcl[256], cur[256], wtot[4];
    __shared__ int mpad_sh;
    __shared__ ushort scidx[PADCAP];
    const int b = blockIdx.x, t = threadIdx.x;
    const int p0r = b * RAWCAP;        // pairs base (u32 units)
    const int p0e = b * PADCAP;        // edge_dst base (u16 units)
    const int m = min(bcur[b * BCUR_STRIDE], RAWCAP);
    const int node0 = b << BK_SHIFT;

    if (t < 256) { arr[t] = 0; cur[t] = 0; }
    __syncthreads();
    for (int i = t; i < m; i += 512)
        atomicAdd(&arr[pairs[p0r + i] >> 16], 1);
    __syncthreads();

    int v = 0, pv = 0, inc = 0;
    if (t < 256) {
        v = arr[t];                    // real degree of local node t
        pv = (v + 7) & ~7;             // padded degree
        inc = pv;
        #pragma unroll
        for (int d = 1; d < 64; d <<= 1) {
            int x = __shfl_up(inc, d);
            if ((t & 63) >= d) inc += x;
        }
        if ((t & 63) == 63) wtot[t >> 6] = inc;
    }
    __syncthreads();
    if (t < 256) {
        const int wid = t >> 6;
        int wpre = 0;
        for (int i = 0; i < wid; ++i) wpre += wtot[i];
        const int excl = wpre + inc - pv;
        nexcl[t] = excl;
        if (node0 + t < n_nodes) {
            offsets[node0 + t] = p0e + excl;
            ncnt[node0 + t] = v;
        }
        if (t == 255) mpad_sh = excl + pv;
    }
    __syncthreads();

    for (int i = t; i < m; i += 512) {
        uint p = pairs[p0r + i];
        int l = (int)(p >> 16);
        int slot = nexcl[l] + atomicAdd(&cur[l], 1);
        scidx[slot] = (ushort)(p & 0xFFFFu);
    }
    __syncthreads();
    if (t < 256) {
        const int base = nexcl[t];
        for (int k = v; k < pv; ++k)   // pad this node's run with zero-row idx
            scidx[base + k] = (ushort)nc;
    }
    __syncthreads();
    const int mp2 = mpad_sh >> 1;      // flush as u32 (mpad multiple of 8)
    uint* ed32 = reinterpret_cast<uint*>(edge_dst);
    const uint* sc32 = reinterpret_cast<const uint*>(scidx);
    const int p0e2 = p0e >> 1;
    for (int i = t; i < mp2; i += 512)
        ed32[p0e2 + i] = sc32[i];
}

// K3: one wave per node, channel-split gather. Lane = (eg = lane>>4, ch = lane&15).
// One uint4 load per lane => 4 complete y-rows (1 KB) per instruction.
// Per-lane f32 accumulators for 8 channels; shfl_xor(16,32) reduces over eg;
// lanes 0-15 store the 512B output row as two float4.
__global__ __launch_bounds__(256) void k_reduce(const ushort* __restrict__ yb,
                                                const int* __restrict__ offsets,
                                                const int* __restrict__ ncnt,
                                                const ushort* __restrict__ edge_dst,
                                                const float* __restrict__ bias,
                                                float* __restrict__ out, int n) {
    int gw = (blockIdx.x * blockDim.x + threadIdx.x) >> 6;
    if (gw >= n) return;
    const int lane = threadIdx.x & 63;
    const int eg = lane >> 4;          // edge slot 0..3
    const int ch = lane & 15;          // 16B channel group
    const int gwu = __builtin_amdgcn_readfirstlane(gw);
    const int s = offsets[gwu];        // u16 units
    const int cnt = ncnt[gwu];
    const int rounds = ((cnt + 7) & ~7) >> 2;   // even (runs padded to 8)

    const ushort* ep = edge_dst + s + eg;
    const char* ybase = reinterpret_cast<const char*>(yb) + ch * 16;

    float a0 = 0.f, a1 = 0.f, a2 = 0.f, a3 = 0.f;
    float a4 = 0.f, a5 = 0.f, a6 = 0.f, a7 = 0.f;
    #pragma unroll 2
    for (int r = 0; r < rounds; ++r) {
        uint c = ep[r * 4];
        uint4 v = *reinterpret_cast<const uint4*>(ybase + (size_t)c * 256);
        a0 += blo(v.x); a1 += bhi(v.x);
        a2 += blo(v.y); a3 += bhi(v.y);
        a4 += blo(v.z); a5 += bhi(v.z);
        a6 += blo(v.w); a7 += bhi(v.w);
    }
    // reduce over the 4 edge slots (lanes ch, ch+16, ch+32, ch+48)
    a0 += __shfl_xor(a0, 16); a0 += __shfl_xor(a0, 32);
    a1 += __shfl_xor(a1, 16); a1 += __shfl_xor(a1, 32);
    a2 += __shfl_xor(a2, 16); a2 += __shfl_xor(a2, 32);
    a3 += __shfl_xor(a3, 16); a3 += __shfl_xor(a3, 32);
    a4 += __shfl_xor(a4, 16); a4 += __shfl_xor(a4, 32);
    a5 += __shfl_xor(a5, 16); a5 += __shfl_xor(a5, 32);
    a6 += __shfl_xor(a6, 16); a6 += __shfl_xor(a6, 32);
    a7 += __shfl_xor(a7, 16); a7 += __shfl_xor(a7, 32);

    if (lane < 16) {
        const float inv = 1.0f / (float)max(cnt, 1);
        const f32x4 bv0 = *reinterpret_cast<const f32x4*>(&bias[ch * 8]);
        const f32x4 bv1 = *reinterpret_cast<const f32x4*>(&bias[ch * 8 + 4]);
        f32x4 o0, o1;
        o0.x = a0 * inv + bv0.x;
        o0.y = a1 * inv + bv0.y;
        o0.z = a2 * inv + bv0.z;
        o0.w = a3 * inv + bv0.w;
        o1.x = a4 * inv + bv1.x;
        o1.y = a5 * inv + bv1.y;
        o1.z = a6 * inv + bv1.z;
        o1.w = a7 * inv + bv1.w;
        float* orow = &out[(size_t)gw * 128 + ch * 8];
        __builtin_nontemporal_store(o0, reinterpret_cast<f32x4*>(orow));
        __builtin_nontemporal_store(o1, reinterpret_cast<f32x4*>(orow + 4));
    }
}

extern "C" void kernel_launch(void* const* d_in, const int* in_sizes, int n_in,
                              void* d_out, int out_size, void* d_ws, size_t ws_size,
                              hipStream_t stream) {
    const float* xc  = (const float*)d_in[1];
    const int*   n2c = (const int*)d_in[2];
    const float* W   = (const float*)d_in[3];
    const float* b   = (const float*)d_in[4];
    float* out = (float*)d_out;

    const int n_nodes   = in_sizes[0] / 128;
    const int n_cliques = in_sizes[1] / 128;
    const int n_edges   = in_sizes[2] / 2;
    const int* nidx = n2c;
    const int* cidx = n2c + n_edges;
    const int nbucket = (n_nodes + ((1 << BK_SHIFT) - 1)) >> BK_SHIFT;   // 391

    // workspace layout (~26 MB)
    char* ws = (char*)d_ws;
    size_t off = 0;
    ushort* yb = (ushort*)(ws + off);     off += (size_t)(n_cliques + 1) * 128 * sizeof(ushort);
    off = (off + 15) & ~(size_t)15;
    uint* pairs = (uint*)(ws + off);      off += (size_t)nbucket * RAWCAP * sizeof(uint);
    ushort* edge_dst = (ushort*)(ws + off); off += (size_t)nbucket * PADCAP * sizeof(ushort);
    off = (off + 15) & ~(size_t)15;
    int* offsets = (int*)(ws + off);      off += (size_t)n_nodes * sizeof(int);
    int* ncnt = (int*)(ws + off);         off += (size_t)n_nodes * sizeof(int);
    int* bcur = (int*)(ws + off);         off += (size_t)NB_MAX * BCUR_STRIDE * sizeof(int);

    (void)hipMemsetAsync(bcur, 0, (size_t)NB_MAX * BCUR_STRIDE * sizeof(int), stream);

    const int gf = (n_edges + FCHUNK - 1) / FCHUNK;      // 391
    const int gt = (n_cliques + 255) / 256;              // 196
    k_front<<<gf + gt, 512, 0, stream>>>(xc, W, yb, n_cliques, nidx, cidx, bcur,
                                         pairs, n_edges, gf);
    k_build<<<nbucket, 512, 0, stream>>>(pairs, bcur, offsets, ncnt, edge_dst,
                                         n_nodes, n_cliques);
    k_reduce<<<((n_nodes) * 64 + 255) / 256, 256, 0, stream>>>(yb, offsets, ncnt, edge_dst, b, out, n_nodes);
}

// Round 14
// 101.314 us; speedup vs baseline: 1.0326x; 1.0326x over previous
//
#include <hip/hip_runtime.h>

// ---------------------------------------------------------------------------
// Clique2NodeConv: out[n] = (mean_{e: node[e]==n} x_clique[clique[e]]) @ W^T + b
// y = bf16(x_clique @ W^T) [MFMA], then bucket-sorted CSR gather-reduce.
// Pipeline (3 kernels + 32KB memset):
//   k_front : fused {MFMA transform, 256 rows/block} + {bucket partition}
//   k_build : per-bucket LDS counting sort (512 thr) -> offsets/ncnt + u16
//             edge_dst, node runs padded to multiple of 8 (zero-row sentinel)
//   k_reduce: one wave per node; one-row-per-instruction uniform gathers
//             (16/8-deep batches), edge ids read as packed u32 pairs
// ---------------------------------------------------------------------------

typedef short bf16x8 __attribute__((ext_vector_type(8)));
typedef float f32x4  __attribute__((ext_vector_type(4)));
typedef float f32x2  __attribute__((ext_vector_type(2)));

#define BK_SHIFT 8
#define NB_MAX 512        // max buckets (n_nodes <= 131072)
#define BCUR_STRIDE 16    // one counter per 64B line
#define RAWCAP 4608       // raw bucket capacity: mean 4096 + 8 sigma
#define PADCAP 6400       // padded capacity (ushort units): RAWCAP + 256*7
#define FCHUNK 4096       // edges per fill block

__device__ inline ushort f2b(float f) {   // f32 -> bf16 RNE
    union { float f; uint u; } v; v.f = f;
    uint r = v.u + 0x7FFFu + ((v.u >> 16) & 1u);
    return (ushort)(r >> 16);
}
__device__ inline float blo(uint v) { union { uint u; float f; } x; x.u = v << 16;        return x.f; }
__device__ inline float bhi(uint v) { union { uint u; float f; } x; x.u = v & 0xFFFF0000u; return x.f; }

struct FillSM {
    int cnt[NB_MAX];
    int sloc[NB_MAX];
    int gbase[NB_MAX];
    int cur[NB_MAX];
    int wtot[8];
    uint   stage[FCHUNK];    // packed (local8<<16)|clique16
    ushort sbkt[FCHUNK];     // bucket id of staged pair
};
struct TransSM { ushort wl[128 * 128]; };   // swizzled bf16 W

// K1 fused: blocks [0,gf) partition edges into bucket regions (bump alloc);
//           blocks [gf,gf+gt) compute y = bf16(xc @ W^T), 256 rows per block.
__global__ __launch_bounds__(512) void k_front(const float* __restrict__ xc,
                                               const float* __restrict__ W,
                                               ushort* __restrict__ yb, int nc,
                                               const int* __restrict__ nidx,
                                               const int* __restrict__ cidx,
                                               int* __restrict__ bcur,
                                               uint* __restrict__ pairs,
                                               int ne, int gf) {
    __shared__ union USM { FillSM f; TransSM tr; } sm;
    const int t = threadIdx.x;
    const int lane = t & 63, wid = t >> 6;

    if ((int)blockIdx.x < gf) {
        // ----- bucket partition -----
        const int e0 = blockIdx.x * FCHUNK;
        const int e1 = min(e0 + FCHUNK, ne);
        sm.f.cnt[t] = 0;
        sm.f.cur[t] = 0;
        __syncthreads();

        int nn[8], cc[8];
        #pragma unroll
        for (int k = 0; k < 8; ++k) {
            int i = e0 + k * 512 + t;
            if (i < e1) {
                nn[k] = nidx[i];
                cc[k] = cidx[i];
                atomicAdd(&sm.f.cnt[nn[k] >> BK_SHIFT], 1);
            } else nn[k] = -1;
        }
        __syncthreads();

        // exclusive scan of 512 bucket counts
        int v = sm.f.cnt[t];
        int inc = v;
        #pragma unroll
        for (int d = 1; d < 64; d <<= 1) { int x = __shfl_up(inc, d); if (lane >= d) inc += x; }
        if (lane == 63) sm.f.wtot[wid] = inc;
        __syncthreads();
        int wpre = 0;
        for (int i = 0; i < wid; ++i) wpre += sm.f.wtot[i];
        int excl = wpre + inc - v;
        sm.f.sloc[t] = excl;
        if (v > 0) sm.f.gbase[t] = t * RAWCAP + atomicAdd(&bcur[t * BCUR_STRIDE], v);
        __syncthreads();

        // group pairs by bucket in LDS
        #pragma unroll
        for (int k = 0; k < 8; ++k) {
            if (nn[k] >= 0) {
                int b = nn[k] >> BK_SHIFT;
                int slot = sm.f.sloc[b] + atomicAdd(&sm.f.cur[b], 1);
                sm.f.stage[slot] = ((uint)(nn[k] & 255) << 16) | (uint)cc[k];
                sm.f.sbkt[slot] = (ushort)b;
            }
        }
        __syncthreads();

        // flush coalesced runs to bucket regions
        const int m = e1 - e0;
        for (int i = t; i < m; i += 512) {
            int b = sm.f.sbkt[i];
            pairs[(size_t)sm.f.gbase[b] + (i - sm.f.sloc[b])] = sm.f.stage[i];
        }
    } else {
        // ----- transform: y = bf16(xc @ W^T), 256 rows per block -----
        const int bid = blockIdx.x - gf;
        if (bid == 0 && t < 64)     // zero the pad row y[nc]
            reinterpret_cast<uint*>(&yb[(size_t)nc * 128])[t] = 0u;
        for (int i = 0; i < 8; ++i) {
            int idx = (i * 512 + t) * 4;
            float4 w4 = *reinterpret_cast<const float4*>(&W[idx]);
            int o = idx >> 7, k = idx & 127;
            ushort4 h;
            h.x = f2b(w4.x); h.y = f2b(w4.y); h.z = f2b(w4.z); h.w = f2b(w4.w);
            int byte = o * 256 + k * 2;
            byte ^= (o & 7) << 4;
            *reinterpret_cast<ushort4*>(reinterpret_cast<char*>(sm.tr.wl) + byte) = h;
        }
        __syncthreads();

        const int lrow = lane & 15;
        const int lk = lane >> 4;
        for (int g = 0; g < 2; ++g) {
            const int r0 = bid * 256 + g * 128 + wid * 16;
            const bool rowok = (r0 + lrow) < nc;
            const float* arow = &xc[(size_t)(r0 + lrow) * 128];

            bf16x8 afrag[4];
            for (int kb = 0; kb < 4; ++kb) {
                float4 a0 = make_float4(0.f, 0.f, 0.f, 0.f), a1 = a0;
                if (rowok) {
                    int k0 = kb * 32 + lk * 8;
                    a0 = *reinterpret_cast<const float4*>(&arow[k0]);
                    a1 = *reinterpret_cast<const float4*>(&arow[k0 + 4]);
                }
                bf16x8 a;
                a[0] = (short)f2b(a0.x); a[1] = (short)f2b(a0.y);
                a[2] = (short)f2b(a0.z); a[3] = (short)f2b(a0.w);
                a[4] = (short)f2b(a1.x); a[5] = (short)f2b(a1.y);
                a[6] = (short)f2b(a1.z); a[7] = (short)f2b(a1.w);
                afrag[kb] = a;
            }

            for (int ct = 0; ct < 8; ++ct) {
                f32x4 c = {0.f, 0.f, 0.f, 0.f};
                const int o = ct * 16 + lrow;
                #pragma unroll
                for (int kb = 0; kb < 4; ++kb) {
                    int byte = o * 256 + (kb * 32 + lk * 8) * 2;
                    byte ^= (o & 7) << 4;
                    bf16x8 bb = *reinterpret_cast<const bf16x8*>(reinterpret_cast<const char*>(sm.tr.wl) + byte);
                    c = __builtin_amdgcn_mfma_f32_16x16x32_bf16(afrag[kb], bb, c, 0, 0, 0);
                }
                const int orow = r0 + lk * 4;
                #pragma unroll
                for (int j = 0; j < 4; ++j)
                    if (orow + j < nc)
                        yb[(size_t)(orow + j) * 128 + ct * 16 + lrow] = f2b(c[j]);
            }
        }
    }
}

// K2: one block (512 thr) per bucket: LDS hist, PADDED scan (runs rounded to 8),
// counting sort into u16 scidx with zero-row pad entries, stream edge_dst(u16).
__global__ __launch_bounds__(512) void k_build(const uint* __restrict__ pairs,
                                               const int* __restrict__ bcur,
                                               int* __restrict__ offsets,
                                               int* __restrict__ ncnt,
                                               ushort* __restrict__ edge_dst,
                                               int n_nodes, int nc) {
    __shared__ int arr[256], nexcl[256], cur[256], wtot[4];
    __shared__ int mpad_sh;
    __shared__ ushort scidx[PADCAP];
    const int b = blockIdx.x, t = threadIdx.x;
    const int p0r = b * RAWCAP;        // pairs base (u32 units)
    const int p0e = b * PADCAP;        // edge_dst base (u16 units)
    const int m = min(bcur[b * BCUR_STRIDE], RAWCAP);
    const int node0 = b << BK_SHIFT;

    if (t < 256) { arr[t] = 0; cur[t] = 0; }
    __syncthreads();
    for (int i = t; i < m; i += 512)
        atomicAdd(&arr[pairs[p0r + i] >> 16], 1);
    __syncthreads();

    int v = 0, pv = 0, inc = 0;
    if (t < 256) {
        v = arr[t];                    // real degree of local node t
        pv = (v + 7) & ~7;             // padded degree
        inc = pv;
        #pragma unroll
        for (int d = 1; d < 64; d <<= 1) {
            int x = __shfl_up(inc, d);
            if ((t & 63) >= d) inc += x;
        }
        if ((t & 63) == 63) wtot[t >> 6] = inc;
    }
    __syncthreads();
    if (t < 256) {
        const int wid = t >> 6;
        int wpre = 0;
        for (int i = 0; i < wid; ++i) wpre += wtot[i];
        const int excl = wpre + inc - pv;
        nexcl[t] = excl;
        if (node0 + t < n_nodes) {
            offsets[node0 + t] = p0e + excl;
            ncnt[node0 + t] = v;
        }
        if (t == 255) mpad_sh = excl + pv;
    }
    __syncthreads();

    for (int i = t; i < m; i += 512) {
        uint p = pairs[p0r + i];
        int l = (int)(p >> 16);
        int slot = nexcl[l] + atomicAdd(&cur[l], 1);
        scidx[slot] = (ushort)(p & 0xFFFFu);
    }
    __syncthreads();
    if (t < 256) {
        const int base = nexcl[t];
        for (int k = v; k < pv; ++k)   // pad this node's run with zero-row idx
            scidx[base + k] = (ushort)nc;
    }
    __syncthreads();
    const int mp2 = mpad_sh >> 1;      // flush as u32 (mpad multiple of 8)
    uint* ed32 = reinterpret_cast<uint*>(edge_dst);
    const uint* sc32 = reinterpret_cast<const uint*>(scidx);
    const int p0e2 = p0e >> 1;
    for (int i = t; i < mp2; i += 512)
        ed32[p0e2 + i] = sc32[i];
}

// K3: one wave per node. One-row-per-instruction uniform gathers, 16/8-deep
// batches; edge ids read as packed u32 pairs; split f32 accumulators.
__global__ __launch_bounds__(256) void k_reduce(const ushort* __restrict__ yb,
                                                const int* __restrict__ offsets,
                                                const int* __restrict__ ncnt,
                                                const ushort* __restrict__ edge_dst,
                                                const float* __restrict__ bias,
                                                float* __restrict__ out, int n) {
    int gw = (blockIdx.x * blockDim.x + threadIdx.x) >> 6;
    if (gw >= n) return;
    const int lane = threadIdx.x & 63;
    const int gwu = __builtin_amdgcn_readfirstlane(gw);
    const int s = offsets[gwu];          // u16 units, multiple of 8
    const int cnt = ncnt[gwu];
    const int e = (cnt + 7) & ~7;        // padded run length
    const uint* edp = reinterpret_cast<const uint*>(edge_dst + s);
    const char* ybase = reinterpret_cast<const char*>(yb) + lane * 4;

    float ax0 = 0.f, ay0 = 0.f, ax1 = 0.f, ay1 = 0.f;
    int j = 0, q32 = 0;
    for (; j + 16 <= e; j += 16) {
        uint w[8];
        #pragma unroll
        for (int q = 0; q < 8; ++q) w[q] = edp[q32 + q];
        q32 += 8;
        uint v[16];
        #pragma unroll
        for (int q = 0; q < 8; ++q) {
            uint c0 = w[q] & 0xFFFFu, c1 = w[q] >> 16;
            v[2 * q]     = *reinterpret_cast<const uint*>(ybase + (size_t)c0 * 256);
            v[2 * q + 1] = *reinterpret_cast<const uint*>(ybase + (size_t)c1 * 256);
        }
        #pragma unroll
        for (int u = 0; u < 16; u += 2) {
            ax0 += blo(v[u]);     ay0 += bhi(v[u]);
            ax1 += blo(v[u + 1]); ay1 += bhi(v[u + 1]);
        }
    }
    if (j < e) {   // exactly one 8-batch remains (runs are multiples of 8)
        uint w[4];
        #pragma unroll
        for (int q = 0; q < 4; ++q) w[q] = edp[q32 + q];
        uint v[8];
        #pragma unroll
        for (int q = 0; q < 4; ++q) {
            uint c0 = w[q] & 0xFFFFu, c1 = w[q] >> 16;
            v[2 * q]     = *reinterpret_cast<const uint*>(ybase + (size_t)c0 * 256);
            v[2 * q + 1] = *reinterpret_cast<const uint*>(ybase + (size_t)c1 * 256);
        }
        #pragma unroll
        for (int u = 0; u < 8; u += 2) {
            ax0 += blo(v[u]);     ay0 += bhi(v[u]);
            ax1 += blo(v[u + 1]); ay1 += bhi(v[u + 1]);
        }
    }
    float ax = ax0 + ax1, ay = ay0 + ay1;
    float inv = 1.0f / (float)max(cnt, 1);
    f32x2 bv = *reinterpret_cast<const f32x2*>(&bias[lane * 2]);
    f32x2 o;
    o.x = ax * inv + bv.x;
    o.y = ay * inv + bv.y;
    __builtin_nontemporal_store(o, reinterpret_cast<f32x2*>(&out[(size_t)gw * 128 + lane * 2]));
}

extern "C" void kernel_launch(void* const* d_in, const int* in_sizes, int n_in,
                              void* d_out, int out_size, void* d_ws, size_t ws_size,
                              hipStream_t stream) {
    const float* xc  = (const float*)d_in[1];
    const int*   n2c = (const int*)d_in[2];
    const float* W   = (const float*)d_in[3];
    const float* b   = (const float*)d_in[4];
    float* out = (float*)d_out;

    const int n_nodes   = in_sizes[0] / 128;
    const int n_cliques = in_sizes[1] / 128;
    const int n_edges   = in_sizes[2] / 2;
    const int* nidx = n2c;
    const int* cidx = n2c + n_edges;
    const int nbucket = (n_nodes + ((1 << BK_SHIFT) - 1)) >> BK_SHIFT;   // 391

    // workspace layout (~26 MB)
    char* ws = (char*)d_ws;
    size_t off = 0;
    ushort* yb = (ushort*)(ws + off);     off += (size_t)(n_cliques + 1) * 128 * sizeof(ushort);
    off = (off + 15) & ~(size_t)15;
    uint* pairs = (uint*)(ws + off);      off += (size_t)nbucket * RAWCAP * sizeof(uint);
    ushort* edge_dst = (ushort*)(ws + off); off += (size_t)nbucket * PADCAP * sizeof(ushort);
    off = (off + 15) & ~(size_t)15;
    int* offsets = (int*)(ws + off);      off += (size_t)n_nodes * sizeof(int);
    int* ncnt = (int*)(ws + off);         off += (size_t)n_nodes * sizeof(int);
    int* bcur = (int*)(ws + off);         off += (size_t)NB_MAX * BCUR_STRIDE * sizeof(int);

    (void)hipMemsetAsync(bcur, 0, (size_t)NB_MAX * BCUR_STRIDE * sizeof(int), stream);

    const int gf = (n_edges + FCHUNK - 1) / FCHUNK;      // 391
    const int gt = (n_cliques + 255) / 256;              // 196
    k_front<<<gf + gt, 512, 0, stream>>>(xc, W, yb, n_cliques, nidx, cidx, bcur,
                                         pairs, n_edges, gf);
    k_build<<<nbucket, 512, 0, stream>>>(pairs, bcur, offsets, ncnt, edge_dst,
                                         n_nodes, n_cliques);
    k_reduce<<<((n_nodes) * 64 + 255) / 256, 256, 0, stream>>>(yb, offsets, ncnt, edge_dst, b, out, n_nodes);
}

// Round 15
// 95.081 us; speedup vs baseline: 1.1003x; 1.0656x over previous
//
#include <hip/hip_runtime.h>

// ---------------------------------------------------------------------------
// Clique2NodeConv: out[n] = (mean_{e: node[e]==n} x_clique[clique[e]]) @ W^T + b
// y = bf16(x_clique @ W^T) [MFMA], then bucket-sorted CSR gather-reduce.
// Pipeline (3 kernels + 2KB memset):
//   k_front : fused {transform blocks} + {bucket-partition blocks (bump alloc)}
//   k_build : per-bucket LDS counting sort -> offsets/ncnt/edge_dst, with each
//             node's edge run PADDED to a multiple of 8 using a zero-row index
//   k_reduce: one wave per node, unconditional 16/8-wide gather batches
// Best-measured configuration (r8: 94.3 us; k_reduce pinned at its ~52-54 us
// line-fill floor across 6 falsified gather-shape variants).
// ---------------------------------------------------------------------------

typedef short bf16x8 __attribute__((ext_vector_type(8)));
typedef float f32x4  __attribute__((ext_vector_type(4)));
typedef float f32x2  __attribute__((ext_vector_type(2)));
typedef unsigned long long u64;

#define BK_SHIFT 8
#define NB_MAX 512        // max buckets supported (n_nodes <= 131072)
#define RAWCAP 4608       // raw bucket capacity: mean 4096 + 8 sigma (64)
#define PADCAP 6400       // padded capacity: RAWCAP + 256*7
#define FCHUNK 4096       // edges per fill block

__device__ inline ushort f2b(float f) {   // f32 -> bf16 RNE
    union { float f; uint u; } v; v.f = f;
    uint r = v.u + 0x7FFFu + ((v.u >> 16) & 1u);
    return (ushort)(r >> 16);
}
__device__ inline float blo(uint v) { union { uint u; float f; } x; x.u = v << 16;        return x.f; }
__device__ inline float bhi(uint v) { union { uint u; float f; } x; x.u = v & 0xFFFF0000u; return x.f; }

struct FillSM {
    int cnt[NB_MAX];
    int sloc[NB_MAX];
    int gbase[NB_MAX];
    int cur[NB_MAX];
    int wtot[8];
    u64 stage[FCHUNK];
};
struct TransSM { ushort wl[128 * 128]; };   // swizzled bf16 W

// K1 fused: blocks [0,gf) partition edges into bucket regions (bump alloc);
//           blocks [gf,gf+gt) compute y = bf16(xc @ W^T) via MFMA.
__global__ __launch_bounds__(512) void k_front(const float* __restrict__ xc,
                                               const float* __restrict__ W,
                                               ushort* __restrict__ yb, int nc,
                                               const int* __restrict__ nidx,
                                               const int* __restrict__ cidx,
                                               int* __restrict__ bcur,
                                               u64* __restrict__ pairs,
                                               int ne, int gf) {
    __shared__ union USM { FillSM f; TransSM tr; } sm;
    const int t = threadIdx.x;

    if ((int)blockIdx.x < gf) {
        // ----- bucket partition -----
        const int e0 = blockIdx.x * FCHUNK;
        const int e1 = min(e0 + FCHUNK, ne);
        sm.f.cnt[t] = 0;
        sm.f.cur[t] = 0;
        __syncthreads();

        int nn[8], cc[8];
        #pragma unroll
        for (int k = 0; k < 8; ++k) {
            int i = e0 + k * 512 + t;
            if (i < e1) {
                nn[k] = nidx[i];
                cc[k] = cidx[i];
                atomicAdd(&sm.f.cnt[nn[k] >> BK_SHIFT], 1);
            } else nn[k] = -1;
        }
        __syncthreads();

        // exclusive scan of 512 bucket counts (wave shfl scan + cross-wave)
        const int lane = t & 63, wid = t >> 6;
        int v = sm.f.cnt[t];
        int inc = v;
        #pragma unroll
        for (int d = 1; d < 64; d <<= 1) {
            int x = __shfl_up(inc, d);
            if (lane >= d) inc += x;
        }
        if (lane == 63) sm.f.wtot[wid] = inc;
        __syncthreads();
        int wpre = 0;
        for (int i = 0; i < wid; ++i) wpre += sm.f.wtot[i];
        int excl = wpre + inc - v;
        sm.f.sloc[t] = excl;
        if (v > 0) sm.f.gbase[t] = t * RAWCAP + atomicAdd(&bcur[t], v);
        __syncthreads();

        // group pairs by bucket in LDS
        #pragma unroll
        for (int k = 0; k < 8; ++k) {
            if (nn[k] >= 0) {
                int b = nn[k] >> BK_SHIFT;
                int slot = sm.f.sloc[b] + atomicAdd(&sm.f.cur[b], 1);
                sm.f.stage[slot] = (u64)(uint)nn[k] | ((u64)(uint)cc[k] << 32);
            }
        }
        __syncthreads();

        // flush coalesced runs to bucket regions
        const int m = e1 - e0;
        for (int i = t; i < m; i += 512) {
            u64 p = sm.f.stage[i];
            int b = (int)((uint)p >> BK_SHIFT);
            pairs[(size_t)sm.f.gbase[b] + (i - sm.f.sloc[b])] = p;
        }
    } else {
        // ----- transform: y = bf16(xc @ W^T) -----
        const int bid = blockIdx.x - gf;
        for (int i = 0; i < 8; ++i) {
            int idx = (i * 512 + t) * 4;
            float4 w4 = *reinterpret_cast<const float4*>(&W[idx]);
            int o = idx >> 7, k = idx & 127;
            ushort4 h;
            h.x = f2b(w4.x); h.y = f2b(w4.y); h.z = f2b(w4.z); h.w = f2b(w4.w);
            int byte = o * 256 + k * 2;
            byte ^= (o & 7) << 4;
            *reinterpret_cast<ushort4*>(reinterpret_cast<char*>(sm.tr.wl) + byte) = h;
        }
        __syncthreads();

        const int wid = t >> 6, lane = t & 63;
        const int lrow = lane & 15;
        const int lk = lane >> 4;
        const int r0 = bid * 128 + wid * 16;
        const bool rowok = (r0 + lrow) < nc;
        const float* arow = &xc[(size_t)(r0 + lrow) * 128];

        bf16x8 afrag[4];
        for (int kb = 0; kb < 4; ++kb) {
            float4 a0 = make_float4(0.f, 0.f, 0.f, 0.f), a1 = a0;
            if (rowok) {
                int k0 = kb * 32 + lk * 8;
                a0 = *reinterpret_cast<const float4*>(&arow[k0]);
                a1 = *reinterpret_cast<const float4*>(&arow[k0 + 4]);
            }
            bf16x8 a;
            a[0] = (short)f2b(a0.x); a[1] = (short)f2b(a0.y);
            a[2] = (short)f2b(a0.z); a[3] = (short)f2b(a0.w);
            a[4] = (short)f2b(a1.x); a[5] = (short)f2b(a1.y);
            a[6] = (short)f2b(a1.z); a[7] = (short)f2b(a1.w);
            afrag[kb] = a;
        }

        for (int ct = 0; ct < 8; ++ct) {
            f32x4 c = {0.f, 0.f, 0.f, 0.f};
            const int o = ct * 16 + lrow;
            #pragma unroll
            for (int kb = 0; kb < 4; ++kb) {
                int byte = o * 256 + (kb * 32 + lk * 8) * 2;
                byte ^= (o & 7) << 4;
                bf16x8 bb = *reinterpret_cast<const bf16x8*>(reinterpret_cast<const char*>(sm.tr.wl) + byte);
                c = __builtin_amdgcn_mfma_f32_16x16x32_bf16(afrag[kb], bb, c, 0, 0, 0);
            }
            const int orow = r0 + lk * 4;
            #pragma unroll
            for (int j = 0; j < 4; ++j)
                if (orow + j < nc)
                    yb[(size_t)(orow + j) * 128 + ct * 16 + lrow] = f2b(c[j]);
        }
    }
}

// K2: one block per bucket: LDS hist, PADDED scan (each node's run rounded up
// to 8), counting sort into scidx with zero-row pad entries, stream edge_dst.
// Block 0 also zeroes y row nc (the pad target).
__global__ __launch_bounds__(256) void k_build(const u64* __restrict__ pairs,
                                               const int* __restrict__ bcur,
                                               int* __restrict__ offsets,
                                               int* __restrict__ ncnt,
                                               int* __restrict__ edge_dst,
                                               ushort* __restrict__ yb,
                                               int n_nodes, int nc) {
    __shared__ int arr[256], nexcl[256], cur[256], wtot[4];
    __shared__ int mpad_sh;
    __shared__ int scidx[PADCAP];
    const int b = blockIdx.x, t = threadIdx.x;
    const int p0r = b * RAWCAP;        // pairs base
    const int p0e = b * PADCAP;        // edge_dst base
    const int m = min(bcur[b], RAWCAP);
    const int node0 = b << BK_SHIFT;

    if (b == 0 && t < 32)              // zero the pad row y[nc]
        reinterpret_cast<uint2*>(&yb[(size_t)nc * 128])[t] = make_uint2(0u, 0u);

    arr[t] = 0; cur[t] = 0;
    __syncthreads();
    for (int i = t; i < m; i += 256)
        atomicAdd(&arr[(int)((uint)pairs[p0r + i]) & 255], 1);
    __syncthreads();

    const int lane = t & 63, wid = t >> 6;
    const int v = arr[t];              // real degree of local node t
    const int pv = (v + 7) & ~7;       // padded degree
    int inc = pv;
    #pragma unroll
    for (int d = 1; d < 64; d <<= 1) {
        int x = __shfl_up(inc, d);
        if (lane >= d) inc += x;
    }
    if (lane == 63) wtot[wid] = inc;
    __syncthreads();
    int wpre = 0;
    for (int i = 0; i < wid; ++i) wpre += wtot[i];
    const int excl = wpre + inc - pv;  // padded exclusive prefix
    nexcl[t] = excl;
    if (node0 + t < n_nodes) {
        offsets[node0 + t] = p0e + excl;
        ncnt[node0 + t] = v;
    }
    if (t == 255) mpad_sh = excl + pv;
    __syncthreads();

    for (int i = t; i < m; i += 256) {
        u64 p = pairs[p0r + i];
        int l = (int)((uint)p) & 255;
        int slot = nexcl[l] + atomicAdd(&cur[l], 1);
        scidx[slot] = (int)(p >> 32);
    }
    __syncthreads();
    for (int k = v; k < pv; ++k)       // pad this node's run with zero-row idx
        scidx[excl + k] = nc;
    __syncthreads();
    const int mp = mpad_sh;
    for (int i = t; i < mp; i += 256)
        edge_dst[p0e + i] = scidx[i];
}

// K3: one wave per node; SGPR CSR range; unconditional 16/8-wide gather batches
// (edge runs are padded to a multiple of 8 with the zero-row index).
__global__ __launch_bounds__(256) void k_reduce(const ushort* __restrict__ yb,
                                                const int* __restrict__ offsets,
                                                const int* __restrict__ ncnt,
                                                const int* __restrict__ edge_dst,
                                                const float* __restrict__ bias,
                                                float* __restrict__ out, int n) {
    int gw = (blockIdx.x * blockDim.x + threadIdx.x) >> 6;
    if (gw >= n) return;
    const int lane = threadIdx.x & 63;
    const int gwu = __builtin_amdgcn_readfirstlane(gw);
    const int s = offsets[gwu];
    const int cnt = ncnt[gwu];
    const int e = s + ((cnt + 7) & ~7);
    const char* ybase = reinterpret_cast<const char*>(yb) + lane * 4;

    float ax0 = 0.f, ay0 = 0.f, ax1 = 0.f, ay1 = 0.f;
    int j = s;
    for (; j + 16 <= e; j += 16) {
        uint v[16];
        #pragma unroll
        for (int u = 0; u < 16; ++u) {
            int c = edge_dst[j + u];
            v[u] = *reinterpret_cast<const uint*>(ybase + (size_t)c * 256);
        }
        #pragma unroll
        for (int u = 0; u < 16; u += 2) {
            ax0 += blo(v[u]);     ay0 += bhi(v[u]);
            ax1 += blo(v[u + 1]); ay1 += bhi(v[u + 1]);
        }
    }
    if (j < e) {   // exactly one 8-batch remains (runs are multiples of 8)
        uint v[8];
        #pragma unroll
        for (int u = 0; u < 8; ++u) {
            int c = edge_dst[j + u];
            v[u] = *reinterpret_cast<const uint*>(ybase + (size_t)c * 256);
        }
        #pragma unroll
        for (int u = 0; u < 8; u += 2) {
            ax0 += blo(v[u]);     ay0 += bhi(v[u]);
            ax1 += blo(v[u + 1]); ay1 += bhi(v[u + 1]);
        }
    }
    float ax = ax0 + ax1, ay = ay0 + ay1;
    float inv = 1.0f / (float)max(cnt, 1);
    f32x2 bv = *reinterpret_cast<const f32x2*>(&bias[lane * 2]);
    f32x2 o;
    o.x = ax * inv + bv.x;
    o.y = ay * inv + bv.y;
    __builtin_nontemporal_store(o, reinterpret_cast<f32x2*>(&out[(size_t)gw * 128 + lane * 2]));
}

extern "C" void kernel_launch(void* const* d_in, const int* in_sizes, int n_in,
                              void* d_out, int out_size, void* d_ws, size_t ws_size,
                              hipStream_t stream) {
    const float* xc  = (const float*)d_in[1];
    const int*   n2c = (const int*)d_in[2];
    const float* W   = (const float*)d_in[3];
    const float* b   = (const float*)d_in[4];
    float* out = (float*)d_out;

    const int n_nodes   = in_sizes[0] / 128;
    const int n_cliques = in_sizes[1] / 128;
    const int n_edges   = in_sizes[2] / 2;
    const int* nidx = n2c;
    const int* cidx = n2c + n_edges;
    const int nbucket = (n_nodes + ((1 << BK_SHIFT) - 1)) >> BK_SHIFT;   // 391

    // workspace layout (~39 MB)
    char* ws = (char*)d_ws;
    size_t off = 0;
    ushort* yb = (ushort*)(ws + off);   off += (size_t)(n_cliques + 1) * 128 * sizeof(ushort);
    off = (off + 15) & ~(size_t)15;
    u64* pairs = (u64*)(ws + off);      off += (size_t)nbucket * RAWCAP * sizeof(u64);
    int* edge_dst = (int*)(ws + off);   off += (size_t)nbucket * PADCAP * sizeof(int);
    int* offsets = (int*)(ws + off);    off += (size_t)n_nodes * sizeof(int);
    int* ncnt = (int*)(ws + off);       off += (size_t)n_nodes * sizeof(int);
    int* bcur = (int*)(ws + off);       off += (size_t)NB_MAX * sizeof(int);

    (void)hipMemsetAsync(bcur, 0, (size_t)NB_MAX * sizeof(int), stream);

    const int gf = (n_edges + FCHUNK - 1) / FCHUNK;      // 391
    const int gt = (n_cliques + 127) / 128;              // 391
    k_front<<<gf + gt, 512, 0, stream>>>(xc, W, yb, n_cliques, nidx, cidx, bcur, pairs, n_edges, gf);
    k_build<<<nbucket, 256, 0, stream>>>(pairs, bcur, offsets, ncnt, edge_dst, yb, n_nodes, n_cliques);
    k_reduce<<<(n_nodes * 64 + 255) / 256, 256, 0, stream>>>(yb, offsets, ncnt, edge_dst, b, out, n_nodes);
}